// Round 1
// baseline (1727.721 us; speedup 1.0000x reference)
//
#include <hip/hip_runtime.h>
#include <hip/hip_bf16.h>
#include <cstdint>

// BalancedMamba on MI355X — round 1: fp32 correctness-first.
// B=16 L=4096 DIN=1280 DM=128 N=16 R=8 NL=2
#define B_   16
#define L_   4096
#define DIN_ 1280
#define DM_  128
#define NS_  16
#define RR_  8
#define NL_  2
#define M_   (B_ * L_)      // 65536 tokens
#define NC_  16             // scan chunks over L
#define CL_  (L_ / NC_)     // 256 steps per chunk
#define SUB_ 8              // timesteps staged per LDS refill

__device__ __forceinline__ float silu_f(float x) { return x / (1.f + __expf(-x)); }

// ---------------------------------------------------------------------------
// Generic fp32 GEMM: C[m,n] = sum_k A[m,k] * W[n,k]  (+bias)
// 64x64 tile, BK=16, 256 threads, 4x4 acc per thread.
// Columns n < split go to C0 (row stride = split), optionally += residual.
// Columns n >= split go to C1 (row stride = Nc-split) with silu applied.
// Requires: M%64==0, Nc%64==0, K%16==0, split%64==0.
// ---------------------------------------------------------------------------
__global__ __launch_bounds__(256) void gemm64(
    const float* __restrict__ A, const float* __restrict__ W,
    const float* __restrict__ bias,
    float* __restrict__ C0, float* __restrict__ C1,
    int M, int Nc, int K, int split, int residual)
{
  __shared__ float As[16][68];   // +4 pad: float4-aligned, <=2-way bank alias (free)
  __shared__ float Ws[16][68];
  const int tid = threadIdx.x;
  const int tx = tid & 15, ty = tid >> 4;
  const int n0 = blockIdx.x * 64;
  const int m0 = blockIdx.y * 64;
  const int lrow = tid >> 2;          // 0..63
  const int lcol = (tid & 3) << 2;    // 0,4,8,12
  float acc[4][4] = {{0.f}};
  const float* Ap = A + (size_t)(m0 + lrow) * K + lcol;
  const float* Wp = W + (size_t)(n0 + lrow) * K + lcol;

  for (int k0 = 0; k0 < K; k0 += 16) {
    float4 av = *(const float4*)(Ap + k0);
    float4 wv = *(const float4*)(Wp + k0);
    __syncthreads();   // protect previous iteration's LDS reads
    As[lcol + 0][lrow] = av.x; As[lcol + 1][lrow] = av.y;
    As[lcol + 2][lrow] = av.z; As[lcol + 3][lrow] = av.w;
    Ws[lcol + 0][lrow] = wv.x; Ws[lcol + 1][lrow] = wv.y;
    Ws[lcol + 2][lrow] = wv.z; Ws[lcol + 3][lrow] = wv.w;
    __syncthreads();
#pragma unroll
    for (int kk = 0; kk < 16; ++kk) {
      float4 a = *(const float4*)&As[kk][ty * 4];
      float4 w = *(const float4*)&Ws[kk][tx * 4];
      acc[0][0] += a.x * w.x; acc[0][1] += a.x * w.y; acc[0][2] += a.x * w.z; acc[0][3] += a.x * w.w;
      acc[1][0] += a.y * w.x; acc[1][1] += a.y * w.y; acc[1][2] += a.y * w.z; acc[1][3] += a.y * w.w;
      acc[2][0] += a.z * w.x; acc[2][1] += a.z * w.y; acc[2][2] += a.z * w.z; acc[2][3] += a.z * w.w;
      acc[3][0] += a.w * w.x; acc[3][1] += a.w * w.y; acc[3][2] += a.w * w.z; acc[3][3] += a.w * w.w;
    }
  }

  float4 bv = make_float4(0.f, 0.f, 0.f, 0.f);
  if (bias) bv = *(const float4*)&bias[n0 + tx * 4];
  const bool left = (n0 + tx * 4) < split;   // uniform per block (split%64==0)
#pragma unroll
  for (int i = 0; i < 4; ++i) {
    const int m = m0 + ty * 4 + i;
    float4 v;
    v.x = acc[i][0] + bv.x; v.y = acc[i][1] + bv.y;
    v.z = acc[i][2] + bv.z; v.w = acc[i][3] + bv.w;
    if (left) {
      float4* p = (float4*)(C0 + (size_t)m * split + n0 + tx * 4);
      if (residual) { float4 o = *p; v.x += o.x; v.y += o.y; v.z += o.z; v.w += o.w; }
      *p = v;
    } else {
      v.x = silu_f(v.x); v.y = silu_f(v.y); v.z = silu_f(v.z); v.w = silu_f(v.w);
      *(float4*)(C1 + (size_t)m * (Nc - split) + (n0 - split) + tx * 4) = v;
    }
  }
}

// ---------------------------------------------------------------------------
// Depthwise causal conv k=2 + silu: u[t] = silu(w0*uraw[t-1] + w1*uraw[t] + cb)
// ---------------------------------------------------------------------------
__global__ __launch_bounds__(256) void convk(
    const float* __restrict__ uraw, const float* __restrict__ cw,
    const float* __restrict__ cb, float* __restrict__ u)
{
  const int idx = blockIdx.x * 256 + threadIdx.x;   // M*DM/4 threads
  const int d4 = (idx & 31) << 2;
  const size_t bt = (size_t)(idx >> 5);
  const int t = (int)(bt & (L_ - 1));
  float4 cur = *(const float4*)&uraw[bt * DM_ + d4];
  float4 prev = make_float4(0.f, 0.f, 0.f, 0.f);
  if (t > 0) prev = *(const float4*)&uraw[(bt - 1) * DM_ + d4];
  float4 wa = *(const float4*)&cw[d4 * 2];       // w[d4][0..1], w[d4+1][0..1]
  float4 wb = *(const float4*)&cw[d4 * 2 + 4];   // w[d4+2][0..1], w[d4+3][0..1]
  float4 cv = *(const float4*)&cb[d4];
  float4 r;
  r.x = silu_f(wa.x * prev.x + wa.y * cur.x + cv.x);
  r.y = silu_f(wa.z * prev.y + wa.w * cur.y + cv.y);
  r.z = silu_f(wb.x * prev.z + wb.y * cur.z + cv.z);
  r.w = silu_f(wb.z * prev.w + wb.w * cur.w + cv.w);
  *(float4*)&u[bt * DM_ + d4] = r;
}

// ---------------------------------------------------------------------------
// Fused x_proj (40x128) -> [dt;B;C], dt_proj (128x8) + softplus.
// Block = 256 threads, 32 tokens. All weights resident in LDS.
// ---------------------------------------------------------------------------
__global__ __launch_bounds__(256) void xproj(
    const float* __restrict__ u,     // [M,128]
    const float* __restrict__ xpw,   // [40,128]
    const float* __restrict__ dtw,   // [128,8]
    const float* __restrict__ dtb,   // [128]
    float* __restrict__ delta,       // [M,128]
    float* __restrict__ BCout)       // [M,32]
{
  __shared__ float u_s[32][132];     // stride 132: float4-aligned
  __shared__ float xp_s[40 * 128];
  __shared__ float dtw_s[128 * 8];
  __shared__ float dtb_s[128];
  __shared__ float proj_s[32][41];   // stride 41: conflict-free scalar access
  const int tid = threadIdx.x;
  const size_t m0 = (size_t)blockIdx.x * 32;

#pragma unroll
  for (int i = 0; i < 16; ++i) {
    int f = tid + i * 256;           // 4096 = 32 tok * 128 d
    u_s[f >> 7][f & 127] = u[(m0 + (f >> 7)) * DM_ + (f & 127)];
  }
  for (int f = tid; f < 40 * 128; f += 256) xp_s[f] = xpw[f];
  for (int f = tid; f < 128 * 8; f += 256) dtw_s[f] = dtw[f];
  if (tid < 128) dtb_s[tid] = dtb[tid];
  __syncthreads();

  {  // phase A: proj[tok][e] = u_row . xp_w[e]
    const int tok = tid & 31, eg = tid >> 5;   // eg 0..7, 5 outputs each
    float pa[5] = {0.f, 0.f, 0.f, 0.f, 0.f};
    for (int dd = 0; dd < 128; dd += 4) {
      float4 uu = *(const float4*)&u_s[tok][dd];
#pragma unroll
      for (int i = 0; i < 5; ++i) {
        float4 xv = *(const float4*)&xp_s[(eg * 5 + i) * 128 + dd];
        pa[i] += uu.x * xv.x + uu.y * xv.y + uu.z * xv.z + uu.w * xv.w;
      }
    }
#pragma unroll
    for (int i = 0; i < 5; ++i) proj_s[tok][eg * 5 + i] = pa[i];
  }
  __syncthreads();

#pragma unroll
  for (int i = 0; i < 4; ++i) {      // B,C out: proj[8:40] -> [M,32] contiguous
    int f = tid + i * 256;
    BCout[m0 * 32 + f] = proj_s[f >> 5][8 + (f & 31)];
  }

  {  // phase B: delta[tok][dd] = softplus(proj[0:8] . dt_w[dd] + dt_b[dd])
    const int tok = tid & 31, dg = tid >> 5;
    float pr[8];
#pragma unroll
    for (int r = 0; r < 8; ++r) pr[r] = proj_s[tok][r];
#pragma unroll
    for (int jj = 0; jj < 16; ++jj) {
      int dd = dg * 16 + jj;
      float acc = dtb_s[dd];
#pragma unroll
      for (int r = 0; r < 8; ++r) acc += pr[r] * dtw_s[dd * 8 + r];
      float sp = (acc > 20.f) ? acc : log1pf(__expf(acc));
      u_s[tok][dd] = sp;             // reuse u_s as staging (barrier-protected)
    }
  }
  __syncthreads();
#pragma unroll
  for (int i = 0; i < 16; ++i) {
    int f = tid + i * 256;
    delta[(m0 + (f >> 7)) * DM_ + (f & 127)] = u_s[f >> 7][f & 127];
  }
}

// ---------------------------------------------------------------------------
// Chunked selective scan, phase 1: per-chunk local scan from h=0.
// Block = 256 thr = 16 d x 16 n; grid (NC, DM/16, B).
// Writes y_local, h_end, P_end(=prod dA over chunk).
// ---------------------------------------------------------------------------
__global__ __launch_bounds__(256) void scan1(
    const float* __restrict__ delta, const float* __restrict__ u,
    const float* __restrict__ BC, const float* __restrict__ alog,
    float* __restrict__ y, float* __restrict__ hend, float* __restrict__ pend)
{
  __shared__ float s_d[SUB_][16], s_u[SUB_][16], s_B[SUB_][16], s_C[SUB_][16], s_y[SUB_][16];
  const int tid = threadIdx.x;
  const int n = tid & 15, dl = (tid >> 4) & 15;
  const int chunk = blockIdx.x, d8 = blockIdx.y, b = blockIdx.z;
  const int d = d8 * 16 + dl;
  const float A = -__expf(alog[d * NS_ + n]);
  float h = 0.f, P = 1.f;
  const int t0 = chunk * CL_;
  const int ls = (tid & 127) >> 4, lj = tid & 15;
  const bool gA = tid < 128;

  for (int ss = 0; ss < CL_; ss += SUB_) {
    const size_t base = (size_t)b * L_ + t0 + ss + ls;
    if (gA) {
      s_d[ls][lj] = delta[base * DM_ + d8 * 16 + lj];
      s_u[ls][lj] = u[base * DM_ + d8 * 16 + lj];
    } else {
      s_B[ls][lj] = BC[base * 32 + lj];
      s_C[ls][lj] = BC[base * 32 + 16 + lj];
    }
    __syncthreads();
#pragma unroll
    for (int s = 0; s < SUB_; ++s) {
      float dlt = s_d[s][dl];
      float dA = __expf(dlt * A);
      float xv = dlt * s_u[s][dl] * s_B[s][n];
      h = fmaf(h, dA, xv);
      P *= dA;
      float yv = h * s_C[s][n];
      yv += __shfl_xor(yv, 1);
      yv += __shfl_xor(yv, 2);
      yv += __shfl_xor(yv, 4);
      yv += __shfl_xor(yv, 8);
      if (n == 0) s_y[s][dl] = yv;
    }
    __syncthreads();
    if (tid < 128)
      y[base * DM_ + d8 * 16 + lj] = s_y[ls][lj];
  }
  const size_t o = (((size_t)b * NC_ + chunk) * DM_ + d) * NS_ + n;
  hend[o] = h;
  pend[o] = P;
}

// phase 2: sequential combine over NC chunks (tiny). grid (DM/16, B).
__global__ __launch_bounds__(256) void scan2(
    const float* __restrict__ hend, const float* __restrict__ pend,
    float* __restrict__ hstart)
{
  const int tid = threadIdx.x;
  const int n = tid & 15, dl = (tid >> 4) & 15;
  const int d = blockIdx.x * 16 + dl, b = blockIdx.y;
  float hs = 0.f;
  for (int c = 0; c < NC_; ++c) {
    const size_t o = (((size_t)b * NC_ + c) * DM_ + d) * NS_ + n;
    hstart[o] = hs;
    hs = hend[o] + pend[o] * hs;
  }
}

// phase 3: y += C.(P_t * h_start); fuse epilogue y = (y + u*Dp) * silu(z).
__global__ __launch_bounds__(256) void scan3(
    const float* __restrict__ delta, const float* __restrict__ u,
    const float* __restrict__ z, const float* __restrict__ BC,
    const float* __restrict__ alog, const float* __restrict__ Dpv,
    const float* __restrict__ hstart, float* __restrict__ y)
{
  __shared__ float s_d[SUB_][16], s_u[SUB_][16], s_z[SUB_][16], s_C[SUB_][16], s_y[SUB_][16];
  const int tid = threadIdx.x;
  const int n = tid & 15, dl = (tid >> 4) & 15;
  const int chunk = blockIdx.x, d8 = blockIdx.y, b = blockIdx.z;
  const int d = d8 * 16 + dl;
  const float A = -__expf(alog[d * NS_ + n]);
  const float hs = hstart[(((size_t)b * NC_ + chunk) * DM_ + d) * NS_ + n];
  float P = 1.f;
  const int t0 = chunk * CL_;
  const int ls = (tid & 127) >> 4, lj = tid & 15;
  const bool gA = tid < 128;

  for (int ss = 0; ss < CL_; ss += SUB_) {
    const size_t base = (size_t)b * L_ + t0 + ss + ls;
    if (gA) {
      s_d[ls][lj] = delta[base * DM_ + d8 * 16 + lj];
      s_u[ls][lj] = u[base * DM_ + d8 * 16 + lj];
    } else {
      s_C[ls][lj] = BC[base * 32 + 16 + lj];
      s_z[ls][lj] = z[base * DM_ + d8 * 16 + lj];
    }
    __syncthreads();
#pragma unroll
    for (int s = 0; s < SUB_; ++s) {
      P *= __expf(s_d[s][dl] * A);
      float yv = (P * hs) * s_C[s][n];
      yv += __shfl_xor(yv, 1);
      yv += __shfl_xor(yv, 2);
      yv += __shfl_xor(yv, 4);
      yv += __shfl_xor(yv, 8);
      if (n == 0) s_y[s][dl] = yv;
    }
    __syncthreads();
    if (tid < 128) {
      const size_t g = base * DM_ + d8 * 16 + lj;
      y[g] = (y[g] + s_y[ls][lj] + s_u[ls][lj] * Dpv[d8 * 16 + lj]) * s_z[ls][lj];
    }
  }
}

// ---------------------------------------------------------------------------
// LayerNorm + partial mean-pool. Block = (b, 256-token chunk), wave per token.
// partial[b][chunk][d] = sum over chunk of (h-mu)*rstd  (deterministic, no atomics)
// ---------------------------------------------------------------------------
__global__ __launch_bounds__(256) void lnpool1(
    const float* __restrict__ h, float* __restrict__ partial)
{
  const int b = blockIdx.y, ch = blockIdx.x;
  const int tid = threadIdx.x, wave = tid >> 6, lane = tid & 63;
  float a0 = 0.f, a1 = 0.f;
  const int tbase = ch * 256 + wave * 64;
  for (int i = 0; i < 64; ++i) {
    const float* row = h + ((size_t)b * L_ + tbase + i) * DM_;
    float x0 = row[lane], x1 = row[lane + 64];
    float s = x0 + x1, sq = x0 * x0 + x1 * x1;
    for (int off = 32; off; off >>= 1) { s += __shfl_xor(s, off); sq += __shfl_xor(sq, off); }
    float mu = s * (1.f / 128.f);
    float var = sq * (1.f / 128.f) - mu * mu;
    float rstd = rsqrtf(var + 1e-5f);
    a0 += (x0 - mu) * rstd;
    a1 += (x1 - mu) * rstd;
  }
  __shared__ float ps[4][128];
  ps[wave][lane] = a0;
  ps[wave][lane + 64] = a1;
  __syncthreads();
  if (tid < 128)
    partial[((size_t)b * 16 + ch) * DM_ + tid] = ps[0][tid] + ps[1][tid] + ps[2][tid] + ps[3][tid];
}

// Final reduce + LN affine + classifier head. One block.
__global__ __launch_bounds__(256) void headk(
    const float* __restrict__ partial,
    const float* __restrict__ lng, const float* __restrict__ lnb,
    const float* __restrict__ c1w, const float* __restrict__ c1b,
    const float* __restrict__ c2w, const float* __restrict__ c2b,
    float* __restrict__ out)
{
  __shared__ float pool[16][128];
  __shared__ float p1[16][64];
  const int tid = threadIdx.x;
  for (int i = tid; i < 16 * 128; i += 256) {
    int b = i >> 7, dd = i & 127;
    float s = 0.f;
    for (int c = 0; c < 16; ++c) s += partial[((size_t)b * 16 + c) * DM_ + dd];
    pool[b][dd] = s * (1.f / (float)L_) * lng[dd] + lnb[dd];
  }
  __syncthreads();
  for (int i = tid; i < 16 * 64; i += 256) {
    int b = i >> 6, j = i & 63;
    float acc = c1b[j];
    for (int dd = 0; dd < 128; ++dd) acc += pool[b][dd] * c1w[j * 128 + dd];
    p1[b][j] = fmaxf(acc, 0.f);
  }
  __syncthreads();
  if (tid < 32) {
    int b = tid >> 1, k = tid & 1;
    float acc = c2b[k];
    for (int j = 0; j < 64; ++j) acc += p1[b][j] * c2w[k * 64 + j];
    out[b * 2 + k] = acc;
  }
}

// ---------------------------------------------------------------------------
extern "C" void kernel_launch(void* const* d_in, const int* in_sizes, int n_in,
                              void* d_out, int out_size, void* d_ws, size_t ws_size,
                              hipStream_t stream)
{
  (void)in_sizes; (void)n_in; (void)out_size; (void)ws_size;
  const float* x    = (const float*)d_in[0];
  const float* ipw  = (const float*)d_in[1];
  const float* ipb  = (const float*)d_in[2];
  const float* inw  = (const float*)d_in[3];
  const float* cw   = (const float*)d_in[4];
  const float* cb   = (const float*)d_in[5];
  const float* xpw  = (const float*)d_in[6];
  const float* dtw  = (const float*)d_in[7];
  const float* dtb  = (const float*)d_in[8];
  const float* alog = (const float*)d_in[9];
  const float* Dpv  = (const float*)d_in[10];
  const float* outw = (const float*)d_in[11];
  const float* lng  = (const float*)d_in[12];
  const float* lnb  = (const float*)d_in[13];
  const float* c1w  = (const float*)d_in[14];
  const float* c1b  = (const float*)d_in[15];
  const float* c2w  = (const float*)d_in[16];
  const float* c2b  = (const float*)d_in[17];

  float* ws = (float*)d_ws;
  const size_t SZ = (size_t)M_ * DM_;            // 8,388,608 floats
  float* h      = ws;                            // [M,128]
  float* yraw   = h + SZ;                        // u_raw, later reused as y
  float* zbuf   = yraw + SZ;                     // silu(z)
  float* ubuf   = zbuf + SZ;                     // post-conv u
  float* dbuf   = ubuf + SZ;                     // delta
  float* bc     = dbuf + SZ;                     // [M,32]
  float* hend   = bc + (size_t)M_ * 32;
  float* pend   = hend + (size_t)B_ * NC_ * DM_ * NS_;
  float* hstart = pend + (size_t)B_ * NC_ * DM_ * NS_;
  float* part   = hstart + (size_t)B_ * NC_ * DM_ * NS_;
  // total ~45.6M floats = ~183 MB of d_ws

  // input projection: h = x @ ip_w^T + ip_b
  gemm64<<<dim3(DM_ / 64, M_ / 64), 256, 0, stream>>>(
      x, ipw, ipb, h, nullptr, M_, DM_, DIN_, DM_, 0);

  for (int l = 0; l < NL_; ++l) {
    // in_proj -> u_raw (cols 0..127) and silu(z) (cols 128..255)
    gemm64<<<dim3(256 / 64, M_ / 64), 256, 0, stream>>>(
        h, inw + (size_t)l * 256 * DM_, nullptr, yraw, zbuf, M_, 256, DM_, DM_, 0);
    convk<<<(M_ * DM_ / 4) / 256, 256, 0, stream>>>(
        yraw, cw + l * DM_ * 2, cb + l * DM_, ubuf);
    xproj<<<M_ / 32, 256, 0, stream>>>(
        ubuf, xpw + l * 40 * DM_, dtw + l * DM_ * RR_, dtb + l * DM_, dbuf, bc);
    scan1<<<dim3(NC_, DM_ / 16, B_), 256, 0, stream>>>(
        dbuf, ubuf, bc, alog + l * DM_ * NS_, yraw, hend, pend);
    scan2<<<dim3(DM_ / 16, B_), 256, 0, stream>>>(hend, pend, hstart);
    scan3<<<dim3(NC_, DM_ / 16, B_), 256, 0, stream>>>(
        dbuf, ubuf, zbuf, bc, alog + l * DM_ * NS_, Dpv + l * DM_, hstart, yraw);
    // out_proj with fused residual: h += y @ out_w^T
    gemm64<<<dim3(DM_ / 64, M_ / 64), 256, 0, stream>>>(
        yraw, outw + (size_t)l * DM_ * DM_, nullptr, h, nullptr, M_, DM_, DM_, DM_, 1);
  }

  lnpool1<<<dim3(16, B_), 256, 0, stream>>>(h, part);
  headk<<<1, 256, 0, stream>>>(part, lng, lnb, c1w, c1b, c2w, c2b, (float*)d_out);
}

// Round 2
// 1378.425 us; speedup vs baseline: 1.2534x; 1.2534x over previous
//
#include <hip/hip_runtime.h>
#include <hip/hip_bf16.h>
#include <cstdint>

// BalancedMamba on MI355X — round 2: bf16-MFMA GEMMs, fp32 everything else.
// B=16 L=4096 DIN=1280 DM=128 N=16 R=8 NL=2
#define B_   16
#define L_   4096
#define DIN_ 1280
#define DM_  128
#define NS_  16
#define RR_  8
#define NL_  2
#define M_   (B_ * L_)      // 65536 tokens
#define NC_  16             // scan chunks over L
#define CL_  (L_ / NC_)     // 256 steps per chunk
#define SUB_ 8              // timesteps staged per LDS refill

typedef short short8 __attribute__((ext_vector_type(8)));
typedef float f32x4  __attribute__((ext_vector_type(4)));
typedef unsigned short ushort;
typedef ushort ushort4v __attribute__((ext_vector_type(4)));

__device__ __forceinline__ float silu_f(float x) { return x / (1.f + __expf(-x)); }

__device__ __forceinline__ ushort f2bf(float f) {   // RNE fp32 -> bf16
  union { float f; uint32_t u; } v; v.f = f;
  uint32_t u = v.u;
  u += 0x7fffu + ((u >> 16) & 1u);
  return (ushort)(u >> 16);
}

// ---------------------------------------------------------------------------
// bf16-MFMA GEMM: C[m,n] = sum_k A[m,k]*W[n,k] (+bias), A,W fp32 in global,
// converted to bf16 (RNE) during LDS staging. 128x128 tile, BK=32,
// 256 thr = 4 waves, each wave 64x64 via 4x4 grid of 16x16x32 MFMA.
// Block-column n0<split -> C0 (stride split, optional residual add);
// n0>=split -> C1 (stride Nc-split) with silu. Requires split%128==0.
// ---------------------------------------------------------------------------
#define LDK 40   // padded LDS row stride in shorts (80 B, 16B-aligned, breaks pow2)

__global__ __launch_bounds__(256) void gemm_mfma(
    const float* __restrict__ A, const float* __restrict__ W,
    const float* __restrict__ bias,
    float* __restrict__ C0, float* __restrict__ C1,
    int M, int Nc, int K, int split, int residual)
{
  __shared__ ushort As[128 * LDK];
  __shared__ ushort Ws[128 * LDK];
  const int tid = threadIdx.x;
  const int n0 = blockIdx.x * 128;
  const int m0 = blockIdx.y * 128;

  // staging: thread -> (row, 16-wide k-slab)
  const int srow = tid >> 1;
  const int scol = (tid & 1) << 4;          // 0 or 16
  const float* gA = A + (size_t)(m0 + srow) * K + scol;
  const float* gW = W + (size_t)(n0 + srow) * K + scol;

  const int lane = tid & 63;
  const int wv = tid >> 6;
  const int wm = (wv & 1) * 64, wn = (wv >> 1) * 64;
  const int ln15 = lane & 15, quad = lane >> 4;

  f32x4 acc[4][4];
#pragma unroll
  for (int i = 0; i < 4; ++i)
#pragma unroll
    for (int j = 0; j < 4; ++j) acc[i][j] = (f32x4){0.f, 0.f, 0.f, 0.f};

  float4 fa[4], fw[4];
#pragma unroll
  for (int j = 0; j < 4; ++j) {
    fa[j] = *(const float4*)(gA + j * 4);
    fw[j] = *(const float4*)(gW + j * 4);
  }

  for (int k0 = 0; k0 < K; k0 += 32) {
    __syncthreads();              // previous iteration's LDS reads done
#pragma unroll
    for (int j = 0; j < 4; ++j) {
      ushort4v a4 = { f2bf(fa[j].x), f2bf(fa[j].y), f2bf(fa[j].z), f2bf(fa[j].w) };
      ushort4v w4 = { f2bf(fw[j].x), f2bf(fw[j].y), f2bf(fw[j].z), f2bf(fw[j].w) };
      *(ushort4v*)&As[srow * LDK + scol + j * 4] = a4;
      *(ushort4v*)&Ws[srow * LDK + scol + j * 4] = w4;
    }
    if (k0 + 32 < K) {            // prefetch next slab while MFMA runs
#pragma unroll
      for (int j = 0; j < 4; ++j) {
        fa[j] = *(const float4*)(gA + k0 + 32 + j * 4);
        fw[j] = *(const float4*)(gW + k0 + 32 + j * 4);
      }
    }
    __syncthreads();
    short8 aF[4], bF[4];
#pragma unroll
    for (int mt = 0; mt < 4; ++mt)
      aF[mt] = *(const short8*)&As[(wm + mt * 16 + ln15) * LDK + quad * 8];
#pragma unroll
    for (int nt = 0; nt < 4; ++nt)
      bF[nt] = *(const short8*)&Ws[(wn + nt * 16 + ln15) * LDK + quad * 8];
#pragma unroll
    for (int mt = 0; mt < 4; ++mt)
#pragma unroll
      for (int nt = 0; nt < 4; ++nt)
        acc[mt][nt] = __builtin_amdgcn_mfma_f32_16x16x32_bf16(
            aF[mt], bF[nt], acc[mt][nt], 0, 0, 0);
  }

  // epilogue: C/D layout col=lane&15, row=quad*4+reg  [m89/m91-verified]
  const bool left = n0 < split;   // block-uniform (split % 128 == 0)
#pragma unroll
  for (int mt = 0; mt < 4; ++mt) {
    const int row = m0 + wm + mt * 16 + quad * 4;
#pragma unroll
    for (int nt = 0; nt < 4; ++nt) {
      const int col = n0 + wn + nt * 16 + ln15;
      const float bv = bias ? bias[col] : 0.f;
#pragma unroll
      for (int r = 0; r < 4; ++r) {
        float v = acc[mt][nt][r] + bv;
        if (left) {
          float* p = C0 + (size_t)(row + r) * split + col;
          if (residual) v += *p;
          *p = v;
        } else {
          C1[(size_t)(row + r) * (Nc - split) + (col - split)] = silu_f(v);
        }
      }
    }
  }
}

// ---------------------------------------------------------------------------
// Depthwise causal conv k=2 + silu: u[t] = silu(w0*uraw[t-1] + w1*uraw[t] + cb)
// ---------------------------------------------------------------------------
__global__ __launch_bounds__(256) void convk(
    const float* __restrict__ uraw, const float* __restrict__ cw,
    const float* __restrict__ cb, float* __restrict__ u)
{
  const int idx = blockIdx.x * 256 + threadIdx.x;   // M*DM/4 threads
  const int d4 = (idx & 31) << 2;
  const size_t bt = (size_t)(idx >> 5);
  const int t = (int)(bt & (L_ - 1));
  float4 cur = *(const float4*)&uraw[bt * DM_ + d4];
  float4 prev = make_float4(0.f, 0.f, 0.f, 0.f);
  if (t > 0) prev = *(const float4*)&uraw[(bt - 1) * DM_ + d4];
  float4 wa = *(const float4*)&cw[d4 * 2];       // w[d4][0..1], w[d4+1][0..1]
  float4 wb = *(const float4*)&cw[d4 * 2 + 4];   // w[d4+2][0..1], w[d4+3][0..1]
  float4 cv = *(const float4*)&cb[d4];
  float4 r;
  r.x = silu_f(wa.x * prev.x + wa.y * cur.x + cv.x);
  r.y = silu_f(wa.z * prev.y + wa.w * cur.y + cv.y);
  r.z = silu_f(wb.x * prev.z + wb.y * cur.z + cv.z);
  r.w = silu_f(wb.z * prev.w + wb.w * cur.w + cv.w);
  *(float4*)&u[bt * DM_ + d4] = r;
}

// ---------------------------------------------------------------------------
// Fused x_proj (40x128) -> [dt;B;C], dt_proj (128x8) + softplus.
// Block = 256 threads, 32 tokens. All weights resident in LDS.
// ---------------------------------------------------------------------------
__global__ __launch_bounds__(256) void xproj(
    const float* __restrict__ u,     // [M,128]
    const float* __restrict__ xpw,   // [40,128]
    const float* __restrict__ dtw,   // [128,8]
    const float* __restrict__ dtb,   // [128]
    float* __restrict__ delta,       // [M,128]
    float* __restrict__ BCout)       // [M,32]
{
  __shared__ float u_s[32][132];     // stride 132: float4-aligned
  __shared__ float xp_s[40 * 128];
  __shared__ float dtw_s[128 * 8];
  __shared__ float dtb_s[128];
  __shared__ float proj_s[32][41];   // stride 41: conflict-free scalar access
  const int tid = threadIdx.x;
  const size_t m0 = (size_t)blockIdx.x * 32;

#pragma unroll
  for (int i = 0; i < 16; ++i) {
    int f = tid + i * 256;           // 4096 = 32 tok * 128 d
    u_s[f >> 7][f & 127] = u[(m0 + (f >> 7)) * DM_ + (f & 127)];
  }
  for (int f = tid; f < 40 * 128; f += 256) xp_s[f] = xpw[f];
  for (int f = tid; f < 128 * 8; f += 256) dtw_s[f] = dtw[f];
  if (tid < 128) dtb_s[tid] = dtb[tid];
  __syncthreads();

  {  // phase A: proj[tok][e] = u_row . xp_w[e]
    const int tok = tid & 31, eg = tid >> 5;   // eg 0..7, 5 outputs each
    float pa[5] = {0.f, 0.f, 0.f, 0.f, 0.f};
    for (int dd = 0; dd < 128; dd += 4) {
      float4 uu = *(const float4*)&u_s[tok][dd];
#pragma unroll
      for (int i = 0; i < 5; ++i) {
        float4 xv = *(const float4*)&xp_s[(eg * 5 + i) * 128 + dd];
        pa[i] += uu.x * xv.x + uu.y * xv.y + uu.z * xv.z + uu.w * xv.w;
      }
    }
#pragma unroll
    for (int i = 0; i < 5; ++i) proj_s[tok][eg * 5 + i] = pa[i];
  }
  __syncthreads();

#pragma unroll
  for (int i = 0; i < 4; ++i) {      // B,C out: proj[8:40] -> [M,32] contiguous
    int f = tid + i * 256;
    BCout[m0 * 32 + f] = proj_s[f >> 5][8 + (f & 31)];
  }

  {  // phase B: delta[tok][dd] = softplus(proj[0:8] . dt_w[dd] + dt_b[dd])
    const int tok = tid & 31, dg = tid >> 5;
    float pr[8];
#pragma unroll
    for (int r = 0; r < 8; ++r) pr[r] = proj_s[tok][r];
#pragma unroll
    for (int jj = 0; jj < 16; ++jj) {
      int dd = dg * 16 + jj;
      float acc = dtb_s[dd];
#pragma unroll
      for (int r = 0; r < 8; ++r) acc += pr[r] * dtw_s[dd * 8 + r];
      float sp = (acc > 20.f) ? acc : log1pf(__expf(acc));
      u_s[tok][dd] = sp;             // reuse u_s as staging (barrier-protected)
    }
  }
  __syncthreads();
#pragma unroll
  for (int i = 0; i < 16; ++i) {
    int f = tid + i * 256;
    delta[(m0 + (f >> 7)) * DM_ + (f & 127)] = u_s[f >> 7][f & 127];
  }
}

// ---------------------------------------------------------------------------
// Chunked selective scan, phase 1: per-chunk local scan from h=0.
// Block = 256 thr = 16 d x 16 n; grid (NC, DM/16, B).
// ---------------------------------------------------------------------------
__global__ __launch_bounds__(256) void scan1(
    const float* __restrict__ delta, const float* __restrict__ u,
    const float* __restrict__ BC, const float* __restrict__ alog,
    float* __restrict__ y, float* __restrict__ hend, float* __restrict__ pend)
{
  __shared__ float s_d[SUB_][16], s_u[SUB_][16], s_B[SUB_][16], s_C[SUB_][16], s_y[SUB_][16];
  const int tid = threadIdx.x;
  const int n = tid & 15, dl = (tid >> 4) & 15;
  const int chunk = blockIdx.x, d8 = blockIdx.y, b = blockIdx.z;
  const int d = d8 * 16 + dl;
  const float A = -__expf(alog[d * NS_ + n]);
  float h = 0.f, P = 1.f;
  const int t0 = chunk * CL_;
  const int ls = (tid & 127) >> 4, lj = tid & 15;
  const bool gA = tid < 128;

  for (int ss = 0; ss < CL_; ss += SUB_) {
    const size_t base = (size_t)b * L_ + t0 + ss + ls;
    if (gA) {
      s_d[ls][lj] = delta[base * DM_ + d8 * 16 + lj];
      s_u[ls][lj] = u[base * DM_ + d8 * 16 + lj];
    } else {
      s_B[ls][lj] = BC[base * 32 + lj];
      s_C[ls][lj] = BC[base * 32 + 16 + lj];
    }
    __syncthreads();
#pragma unroll
    for (int s = 0; s < SUB_; ++s) {
      float dlt = s_d[s][dl];
      float dA = __expf(dlt * A);
      float xv = dlt * s_u[s][dl] * s_B[s][n];
      h = fmaf(h, dA, xv);
      P *= dA;
      float yv = h * s_C[s][n];
      yv += __shfl_xor(yv, 1);
      yv += __shfl_xor(yv, 2);
      yv += __shfl_xor(yv, 4);
      yv += __shfl_xor(yv, 8);
      if (n == 0) s_y[s][dl] = yv;
    }
    __syncthreads();
    if (tid < 128)
      y[base * DM_ + d8 * 16 + lj] = s_y[ls][lj];
  }
  const size_t o = (((size_t)b * NC_ + chunk) * DM_ + d) * NS_ + n;
  hend[o] = h;
  pend[o] = P;
}

// phase 2: sequential combine over NC chunks (tiny). grid (DM/16, B).
__global__ __launch_bounds__(256) void scan2(
    const float* __restrict__ hend, const float* __restrict__ pend,
    float* __restrict__ hstart)
{
  const int tid = threadIdx.x;
  const int n = tid & 15, dl = (tid >> 4) & 15;
  const int d = blockIdx.x * 16 + dl, b = blockIdx.y;
  float hs = 0.f;
  for (int c = 0; c < NC_; ++c) {
    const size_t o = (((size_t)b * NC_ + c) * DM_ + d) * NS_ + n;
    hstart[o] = hs;
    hs = hend[o] + pend[o] * hs;
  }
}

// phase 3: y += C.(P_t * h_start); fuse epilogue y = (y + u*Dp) * silu(z).
__global__ __launch_bounds__(256) void scan3(
    const float* __restrict__ delta, const float* __restrict__ u,
    const float* __restrict__ z, const float* __restrict__ BC,
    const float* __restrict__ alog, const float* __restrict__ Dpv,
    const float* __restrict__ hstart, float* __restrict__ y)
{
  __shared__ float s_d[SUB_][16], s_u[SUB_][16], s_z[SUB_][16], s_C[SUB_][16], s_y[SUB_][16];
  const int tid = threadIdx.x;
  const int n = tid & 15, dl = (tid >> 4) & 15;
  const int chunk = blockIdx.x, d8 = blockIdx.y, b = blockIdx.z;
  const int d = d8 * 16 + dl;
  const float A = -__expf(alog[d * NS_ + n]);
  const float hs = hstart[(((size_t)b * NC_ + chunk) * DM_ + d) * NS_ + n];
  float P = 1.f;
  const int t0 = chunk * CL_;
  const int ls = (tid & 127) >> 4, lj = tid & 15;
  const bool gA = tid < 128;

  for (int ss = 0; ss < CL_; ss += SUB_) {
    const size_t base = (size_t)b * L_ + t0 + ss + ls;
    if (gA) {
      s_d[ls][lj] = delta[base * DM_ + d8 * 16 + lj];
      s_u[ls][lj] = u[base * DM_ + d8 * 16 + lj];
    } else {
      s_C[ls][lj] = BC[base * 32 + 16 + lj];
      s_z[ls][lj] = z[base * DM_ + d8 * 16 + lj];
    }
    __syncthreads();
#pragma unroll
    for (int s = 0; s < SUB_; ++s) {
      P *= __expf(s_d[s][dl] * A);
      float yv = (P * hs) * s_C[s][n];
      yv += __shfl_xor(yv, 1);
      yv += __shfl_xor(yv, 2);
      yv += __shfl_xor(yv, 4);
      yv += __shfl_xor(yv, 8);
      if (n == 0) s_y[s][dl] = yv;
    }
    __syncthreads();
    if (tid < 128) {
      const size_t g = base * DM_ + d8 * 16 + lj;
      y[g] = (y[g] + s_y[ls][lj] + s_u[ls][lj] * Dpv[d8 * 16 + lj]) * s_z[ls][lj];
    }
  }
}

// ---------------------------------------------------------------------------
// LayerNorm + partial mean-pool.
// ---------------------------------------------------------------------------
__global__ __launch_bounds__(256) void lnpool1(
    const float* __restrict__ h, float* __restrict__ partial)
{
  const int b = blockIdx.y, ch = blockIdx.x;
  const int tid = threadIdx.x, wave = tid >> 6, lane = tid & 63;
  float a0 = 0.f, a1 = 0.f;
  const int tbase = ch * 256 + wave * 64;
  for (int i = 0; i < 64; ++i) {
    const float* row = h + ((size_t)b * L_ + tbase + i) * DM_;
    float x0 = row[lane], x1 = row[lane + 64];
    float s = x0 + x1, sq = x0 * x0 + x1 * x1;
    for (int off = 32; off; off >>= 1) { s += __shfl_xor(s, off); sq += __shfl_xor(sq, off); }
    float mu = s * (1.f / 128.f);
    float var = sq * (1.f / 128.f) - mu * mu;
    float rstd = rsqrtf(var + 1e-5f);
    a0 += (x0 - mu) * rstd;
    a1 += (x1 - mu) * rstd;
  }
  __shared__ float ps[4][128];
  ps[wave][lane] = a0;
  ps[wave][lane + 64] = a1;
  __syncthreads();
  if (tid < 128)
    partial[((size_t)b * 16 + ch) * DM_ + tid] = ps[0][tid] + ps[1][tid] + ps[2][tid] + ps[3][tid];
}

// Final reduce + LN affine + classifier head. One block.
__global__ __launch_bounds__(256) void headk(
    const float* __restrict__ partial,
    const float* __restrict__ lng, const float* __restrict__ lnb,
    const float* __restrict__ c1w, const float* __restrict__ c1b,
    const float* __restrict__ c2w, const float* __restrict__ c2b,
    float* __restrict__ out)
{
  __shared__ float pool[16][128];
  __shared__ float p1[16][64];
  const int tid = threadIdx.x;
  for (int i = tid; i < 16 * 128; i += 256) {
    int b = i >> 7, dd = i & 127;
    float s = 0.f;
    for (int c = 0; c < 16; ++c) s += partial[((size_t)b * 16 + c) * DM_ + dd];
    pool[b][dd] = s * (1.f / (float)L_) * lng[dd] + lnb[dd];
  }
  __syncthreads();
  for (int i = tid; i < 16 * 64; i += 256) {
    int b = i >> 6, j = i & 63;
    float acc = c1b[j];
    for (int dd = 0; dd < 128; ++dd) acc += pool[b][dd] * c1w[j * 128 + dd];
    p1[b][j] = fmaxf(acc, 0.f);
  }
  __syncthreads();
  if (tid < 32) {
    int b = tid >> 1, k = tid & 1;
    float acc = c2b[k];
    for (int j = 0; j < 64; ++j) acc += p1[b][j] * c2w[k * 64 + j];
    out[b * 2 + k] = acc;
  }
}

// ---------------------------------------------------------------------------
extern "C" void kernel_launch(void* const* d_in, const int* in_sizes, int n_in,
                              void* d_out, int out_size, void* d_ws, size_t ws_size,
                              hipStream_t stream)
{
  (void)in_sizes; (void)n_in; (void)out_size; (void)ws_size;
  const float* x    = (const float*)d_in[0];
  const float* ipw  = (const float*)d_in[1];
  const float* ipb  = (const float*)d_in[2];
  const float* inw  = (const float*)d_in[3];
  const float* cw   = (const float*)d_in[4];
  const float* cb   = (const float*)d_in[5];
  const float* xpw  = (const float*)d_in[6];
  const float* dtw  = (const float*)d_in[7];
  const float* dtb  = (const float*)d_in[8];
  const float* alog = (const float*)d_in[9];
  const float* Dpv  = (const float*)d_in[10];
  const float* outw = (const float*)d_in[11];
  const float* lng  = (const float*)d_in[12];
  const float* lnb  = (const float*)d_in[13];
  const float* c1w  = (const float*)d_in[14];
  const float* c1b  = (const float*)d_in[15];
  const float* c2w  = (const float*)d_in[16];
  const float* c2b  = (const float*)d_in[17];

  float* ws = (float*)d_ws;
  const size_t SZ = (size_t)M_ * DM_;            // 8,388,608 floats
  float* h      = ws;                            // [M,128]
  float* yraw   = h + SZ;                        // u_raw, later reused as y
  float* zbuf   = yraw + SZ;                     // silu(z)
  float* ubuf   = zbuf + SZ;                     // post-conv u
  float* dbuf   = ubuf + SZ;                     // delta
  float* bc     = dbuf + SZ;                     // [M,32]
  float* hend   = bc + (size_t)M_ * 32;
  float* pend   = hend + (size_t)B_ * NC_ * DM_ * NS_;
  float* hstart = pend + (size_t)B_ * NC_ * DM_ * NS_;
  float* part   = hstart + (size_t)B_ * NC_ * DM_ * NS_;

  // input projection: h = x @ ip_w^T + ip_b   (M x 128, K=1280)
  gemm_mfma<<<dim3(1, M_ / 128), 256, 0, stream>>>(
      x, ipw, ipb, h, nullptr, M_, DM_, DIN_, DM_, 0);

  for (int l = 0; l < NL_; ++l) {
    // in_proj -> u_raw (cols 0..127) and silu(z) (cols 128..255)
    gemm_mfma<<<dim3(2, M_ / 128), 256, 0, stream>>>(
        h, inw + (size_t)l * 256 * DM_, nullptr, yraw, zbuf, M_, 256, DM_, DM_, 0);
    convk<<<(M_ * DM_ / 4) / 256, 256, 0, stream>>>(
        yraw, cw + l * DM_ * 2, cb + l * DM_, ubuf);
    xproj<<<M_ / 32, 256, 0, stream>>>(
        ubuf, xpw + l * 40 * DM_, dtw + l * DM_ * RR_, dtb + l * DM_, dbuf, bc);
    scan1<<<dim3(NC_, DM_ / 16, B_), 256, 0, stream>>>(
        dbuf, ubuf, bc, alog + l * DM_ * NS_, yraw, hend, pend);
    scan2<<<dim3(DM_ / 16, B_), 256, 0, stream>>>(hend, pend, hstart);
    scan3<<<dim3(NC_, DM_ / 16, B_), 256, 0, stream>>>(
        dbuf, ubuf, zbuf, bc, alog + l * DM_ * NS_, Dpv + l * DM_, hstart, yraw);
    // out_proj with fused residual: h += y @ out_w^T
    gemm_mfma<<<dim3(1, M_ / 128), 256, 0, stream>>>(
        yraw, outw + (size_t)l * DM_ * DM_, nullptr, h, nullptr, M_, DM_, DM_, DM_, 1);
  }

  lnpool1<<<dim3(16, B_), 256, 0, stream>>>(h, part);
  headk<<<1, 256, 0, stream>>>(part, lng, lnb, c1w, c1b, c2w, c2b, (float*)d_out);
}

// Round 3
// 914.110 us; speedup vs baseline: 1.8901x; 1.5079x over previous
//
#include <hip/hip_runtime.h>
#include <hip/hip_bf16.h>
#include <cstdint>

// BalancedMamba on MI355X — round 3: register-resident chunked scan (no
// shuffles, no per-step LDS), conv fused into xproj, bf16-MFMA GEMMs.
// B=16 L=4096 DIN=1280 DM=128 N=16 R=8 NL=2
#define B_   16
#define L_   4096
#define DIN_ 1280
#define DM_  128
#define NS_  16
#define RR_  8
#define NL_  2
#define M_   (B_ * L_)      // 65536 tokens
#define NC_  128            // scan chunks over L
#define CL_  (L_ / NC_)     // 32 steps per chunk

typedef short short8 __attribute__((ext_vector_type(8)));
typedef float f32x4  __attribute__((ext_vector_type(4)));
typedef unsigned short ushort;
typedef ushort ushort4v __attribute__((ext_vector_type(4)));

__device__ __forceinline__ float silu_f(float x) { return x / (1.f + __expf(-x)); }

__device__ __forceinline__ ushort f2bf(float f) {   // RNE fp32 -> bf16
  union { float f; uint32_t u; } v; v.f = f;
  uint32_t u = v.u;
  u += 0x7fffu + ((u >> 16) & 1u);
  return (ushort)(u >> 16);
}

// ---------------------------------------------------------------------------
// bf16-MFMA GEMM: C[m,n] = sum_k A[m,k]*W[n,k] (+bias), A,W fp32 in global,
// converted to bf16 (RNE) during LDS staging. 128x128 tile, BK=32,
// 256 thr = 4 waves, each wave 64x64 via 4x4 grid of 16x16x32 MFMA.
// n0<split -> C0 (stride split, optional residual add); else C1 with silu.
// ---------------------------------------------------------------------------
#define LDK 40   // padded LDS row stride in shorts

__global__ __launch_bounds__(256) void gemm_mfma(
    const float* __restrict__ A, const float* __restrict__ W,
    const float* __restrict__ bias,
    float* __restrict__ C0, float* __restrict__ C1,
    int M, int Nc, int K, int split, int residual)
{
  __shared__ ushort As[128 * LDK];
  __shared__ ushort Ws[128 * LDK];
  const int tid = threadIdx.x;
  const int n0 = blockIdx.x * 128;
  const int m0 = blockIdx.y * 128;

  const int srow = tid >> 1;
  const int scol = (tid & 1) << 4;          // 0 or 16
  const float* gA = A + (size_t)(m0 + srow) * K + scol;
  const float* gW = W + (size_t)(n0 + srow) * K + scol;

  const int lane = tid & 63;
  const int wv = tid >> 6;
  const int wm = (wv & 1) * 64, wn = (wv >> 1) * 64;
  const int ln15 = lane & 15, quad = lane >> 4;

  f32x4 acc[4][4];
#pragma unroll
  for (int i = 0; i < 4; ++i)
#pragma unroll
    for (int j = 0; j < 4; ++j) acc[i][j] = (f32x4){0.f, 0.f, 0.f, 0.f};

  float4 fa[4], fw[4];
#pragma unroll
  for (int j = 0; j < 4; ++j) {
    fa[j] = *(const float4*)(gA + j * 4);
    fw[j] = *(const float4*)(gW + j * 4);
  }

  for (int k0 = 0; k0 < K; k0 += 32) {
    __syncthreads();
#pragma unroll
    for (int j = 0; j < 4; ++j) {
      ushort4v a4 = { f2bf(fa[j].x), f2bf(fa[j].y), f2bf(fa[j].z), f2bf(fa[j].w) };
      ushort4v w4 = { f2bf(fw[j].x), f2bf(fw[j].y), f2bf(fw[j].z), f2bf(fw[j].w) };
      *(ushort4v*)&As[srow * LDK + scol + j * 4] = a4;
      *(ushort4v*)&Ws[srow * LDK + scol + j * 4] = w4;
    }
    if (k0 + 32 < K) {
#pragma unroll
      for (int j = 0; j < 4; ++j) {
        fa[j] = *(const float4*)(gA + k0 + 32 + j * 4);
        fw[j] = *(const float4*)(gW + k0 + 32 + j * 4);
      }
    }
    __syncthreads();
    short8 aF[4], bF[4];
#pragma unroll
    for (int mt = 0; mt < 4; ++mt)
      aF[mt] = *(const short8*)&As[(wm + mt * 16 + ln15) * LDK + quad * 8];
#pragma unroll
    for (int nt = 0; nt < 4; ++nt)
      bF[nt] = *(const short8*)&Ws[(wn + nt * 16 + ln15) * LDK + quad * 8];
#pragma unroll
    for (int mt = 0; mt < 4; ++mt)
#pragma unroll
      for (int nt = 0; nt < 4; ++nt)
        acc[mt][nt] = __builtin_amdgcn_mfma_f32_16x16x32_bf16(
            aF[mt], bF[nt], acc[mt][nt], 0, 0, 0);
  }

  const bool left = n0 < split;
#pragma unroll
  for (int mt = 0; mt < 4; ++mt) {
    const int row = m0 + wm + mt * 16 + quad * 4;
#pragma unroll
    for (int nt = 0; nt < 4; ++nt) {
      const int col = n0 + wn + nt * 16 + ln15;
      const float bv = bias ? bias[col] : 0.f;
#pragma unroll
      for (int r = 0; r < 4; ++r) {
        float v = acc[mt][nt][r] + bv;
        if (left) {
          float* p = C0 + (size_t)(row + r) * split + col;
          if (residual) v += *p;
          *p = v;
        } else {
          C1[(size_t)(row + r) * (Nc - split) + (col - split)] = silu_f(v);
        }
      }
    }
  }
}

// ---------------------------------------------------------------------------
// Fused depthwise causal conv(k=2)+silu -> u, then x_proj(40x128)->[dt;B;C],
// dt_proj(128x8)+softplus. Block = 256 thr, 32 tokens (same batch).
// ---------------------------------------------------------------------------
__global__ __launch_bounds__(256) void xpc(
    const float* __restrict__ uraw,  // [M,128] pre-conv
    const float* __restrict__ cw, const float* __restrict__ cb,
    const float* __restrict__ xpw,   // [40,128]
    const float* __restrict__ dtw,   // [128,8]
    const float* __restrict__ dtb,   // [128]
    float* __restrict__ uout,        // [M,128] post-conv (for scans)
    float* __restrict__ delta,       // [M,128]
    float* __restrict__ BCout)       // [M,32]
{
  __shared__ float u_s[32][132];
  __shared__ float xp_s[40 * 128];
  __shared__ float dtw_s[128 * 8];
  __shared__ float dtb_s[128];
  __shared__ float proj_s[32][41];
  const int tid = threadIdx.x;
  const size_t m0 = (size_t)blockIdx.x * 32;
  const int t0 = (int)(m0 & (L_ - 1));

#pragma unroll
  for (int i = 0; i < 16; ++i) {     // conv + silu, 16 elems/thread
    int f = tid + i * 256;
    int tok = f >> 7, dd = f & 127;
    float cur = uraw[(m0 + tok) * DM_ + dd];
    float prev = (t0 + tok > 0) ? uraw[(m0 + tok - 1) * DM_ + dd] : 0.f;
    float v = silu_f(cw[dd * 2] * prev + cw[dd * 2 + 1] * cur + cb[dd]);
    u_s[tok][dd] = v;
    uout[(m0 + tok) * DM_ + dd] = v;
  }
  for (int f = tid; f < 40 * 128; f += 256) xp_s[f] = xpw[f];
  for (int f = tid; f < 128 * 8; f += 256) dtw_s[f] = dtw[f];
  if (tid < 128) dtb_s[tid] = dtb[tid];
  __syncthreads();

  {  // phase A: proj[tok][e] = u_row . xp_w[e]
    const int tok = tid & 31, eg = tid >> 5;
    float pa[5] = {0.f, 0.f, 0.f, 0.f, 0.f};
    for (int dd = 0; dd < 128; dd += 4) {
      float4 uu = *(const float4*)&u_s[tok][dd];
#pragma unroll
      for (int i = 0; i < 5; ++i) {
        float4 xv = *(const float4*)&xp_s[(eg * 5 + i) * 128 + dd];
        pa[i] += uu.x * xv.x + uu.y * xv.y + uu.z * xv.z + uu.w * xv.w;
      }
    }
#pragma unroll
    for (int i = 0; i < 5; ++i) proj_s[tok][eg * 5 + i] = pa[i];
  }
  __syncthreads();

#pragma unroll
  for (int i = 0; i < 4; ++i) {      // B,C -> [M,32]
    int f = tid + i * 256;
    BCout[m0 * 32 + f] = proj_s[f >> 5][8 + (f & 31)];
  }

  {  // phase B: delta = softplus(proj[0:8] . dt_w + dt_b)
    const int tok = tid & 31, dg = tid >> 5;
    float pr[8];
#pragma unroll
    for (int r = 0; r < 8; ++r) pr[r] = proj_s[tok][r];
#pragma unroll
    for (int jj = 0; jj < 16; ++jj) {
      int dd = dg * 16 + jj;
      float acc = dtb_s[dd];
#pragma unroll
      for (int r = 0; r < 8; ++r) acc += pr[r] * dtw_s[dd * 8 + r];
      float sp = (acc > 20.f) ? acc : log1pf(__expf(acc));
      u_s[tok][dd] = sp;
    }
  }
  __syncthreads();
#pragma unroll
  for (int i = 0; i < 16; ++i) {
    int f = tid + i * 256;
    delta[(m0 + (f >> 7)) * DM_ + (f & 127)] = u_s[f >> 7][f & 127];
  }
}

// ---------------------------------------------------------------------------
// Scan phase 1: per-chunk h from 0, register-resident h[16]; stores h_end
// and S = sum(delta) (chunk decay = exp(A_n * S)). Thread = d, block = (chunk,b).
// ---------------------------------------------------------------------------
__global__ __launch_bounds__(128) void scan_h(
    const float* __restrict__ delta, const float* __restrict__ u,
    const float* __restrict__ BC, const float* __restrict__ alog,
    float* __restrict__ hend, float* __restrict__ Ssum)
{
  const int d = threadIdx.x;
  const int chunk = blockIdx.x, b = blockIdx.y;
  float a[NS_], h[NS_];
#pragma unroll
  for (int n = 0; n < NS_; ++n) {
    a[n] = -__expf(alog[d * NS_ + n]);
    h[n] = 0.f;
  }
  float S = 0.f;
  const size_t rowbase = (size_t)b * L_ + (size_t)chunk * CL_;
  float dlt = delta[rowbase * DM_ + d];
  float uu  = u[rowbase * DM_ + d];
  for (int s = 0; s < CL_; ++s) {
    const float* Brow = BC + (rowbase + s) * 32;   // lane-uniform -> s_load
    float Bv[NS_];
#pragma unroll
    for (int n = 0; n < NS_; ++n) Bv[n] = Brow[n];
    float dn = 0.f, un = 0.f;
    if (s + 1 < CL_) {                             // prefetch next step
      dn = delta[(rowbase + s + 1) * DM_ + d];
      un = u[(rowbase + s + 1) * DM_ + d];
    }
    const float du = dlt * uu;
    S += dlt;
#pragma unroll
    for (int n = 0; n < NS_; ++n) {
      float dA = __expf(dlt * a[n]);
      h[n] = fmaf(h[n], dA, du * Bv[n]);
    }
    dlt = dn; uu = un;
  }
  const size_t o = ((size_t)b * NC_ + chunk) * DM_ + d;
  float4* hp = (float4*)(hend + o * NS_);
#pragma unroll
  for (int q = 0; q < 4; ++q)
    hp[q] = make_float4(h[q * 4], h[q * 4 + 1], h[q * 4 + 2], h[q * 4 + 3]);
  Ssum[o] = S;
}

// phase 2: sequential chunk combine. Thread per (b,d,n). 128 blocks.
__global__ __launch_bounds__(256) void scan_comb(
    const float* __restrict__ hend, const float* __restrict__ Ssum,
    const float* __restrict__ alog, float* __restrict__ hstart)
{
  const int idx = blockIdx.x * 256 + threadIdx.x;   // B*DM*NS
  const int n = idx & 15;
  const int d = (idx >> 4) & 127;
  const int b = idx >> 11;
  const float a = -__expf(alog[d * NS_ + n]);
  float hs = 0.f;
  for (int c = 0; c < NC_; ++c) {
    const size_t o = ((size_t)b * NC_ + c) * DM_ + d;
    hstart[o * NS_ + n] = hs;
    hs = hend[o * NS_ + n] + __expf(a * Ssum[o]) * hs;
  }
}

// phase 3: full recompute from h_start, produce y with fused epilogue:
// y = (sum_n h*C + u*Dp) * silu(z)
__global__ __launch_bounds__(128) void scan_y(
    const float* __restrict__ delta, const float* __restrict__ u,
    const float* __restrict__ zbuf, const float* __restrict__ BC,
    const float* __restrict__ alog, const float* __restrict__ Dpv,
    const float* __restrict__ hstart, float* __restrict__ y)
{
  const int d = threadIdx.x;
  const int chunk = blockIdx.x, b = blockIdx.y;
  float a[NS_], h[NS_];
  const size_t o = ((size_t)b * NC_ + chunk) * DM_ + d;
  const float4* hp = (const float4*)(hstart + o * NS_);
#pragma unroll
  for (int q = 0; q < 4; ++q) {
    float4 v = hp[q];
    h[q * 4] = v.x; h[q * 4 + 1] = v.y; h[q * 4 + 2] = v.z; h[q * 4 + 3] = v.w;
  }
#pragma unroll
  for (int n = 0; n < NS_; ++n) a[n] = -__expf(alog[d * NS_ + n]);
  const float Dd = Dpv[d];
  const size_t rowbase = (size_t)b * L_ + (size_t)chunk * CL_;
  float dlt = delta[rowbase * DM_ + d];
  float uu  = u[rowbase * DM_ + d];
  float zz  = zbuf[rowbase * DM_ + d];
  for (int s = 0; s < CL_; ++s) {
    const float* Brow = BC + (rowbase + s) * 32;   // lane-uniform
    float Bv[NS_], Cv[NS_];
#pragma unroll
    for (int n = 0; n < NS_; ++n) { Bv[n] = Brow[n]; Cv[n] = Brow[16 + n]; }
    float dn = 0.f, un = 0.f, zn = 0.f;
    if (s + 1 < CL_) {
      dn = delta[(rowbase + s + 1) * DM_ + d];
      un = u[(rowbase + s + 1) * DM_ + d];
      zn = zbuf[(rowbase + s + 1) * DM_ + d];
    }
    const float du = dlt * uu;
    float yv = uu * Dd;
#pragma unroll
    for (int n = 0; n < NS_; ++n) {
      float dA = __expf(dlt * a[n]);
      h[n] = fmaf(h[n], dA, du * Bv[n]);
      yv = fmaf(h[n], Cv[n], yv);
    }
    y[(rowbase + s) * DM_ + d] = yv * zz;
    dlt = dn; uu = un; zz = zn;
  }
}

// ---------------------------------------------------------------------------
// LayerNorm + partial mean-pool.
// ---------------------------------------------------------------------------
__global__ __launch_bounds__(256) void lnpool1(
    const float* __restrict__ h, float* __restrict__ partial)
{
  const int b = blockIdx.y, ch = blockIdx.x;
  const int tid = threadIdx.x, wave = tid >> 6, lane = tid & 63;
  float a0 = 0.f, a1 = 0.f;
  const int tbase = ch * 256 + wave * 64;
  for (int i = 0; i < 64; ++i) {
    const float* row = h + ((size_t)b * L_ + tbase + i) * DM_;
    float x0 = row[lane], x1 = row[lane + 64];
    float s = x0 + x1, sq = x0 * x0 + x1 * x1;
    for (int off = 32; off; off >>= 1) { s += __shfl_xor(s, off); sq += __shfl_xor(sq, off); }
    float mu = s * (1.f / 128.f);
    float var = sq * (1.f / 128.f) - mu * mu;
    float rstd = rsqrtf(var + 1e-5f);
    a0 += (x0 - mu) * rstd;
    a1 += (x1 - mu) * rstd;
  }
  __shared__ float ps[4][128];
  ps[wave][lane] = a0;
  ps[wave][lane + 64] = a1;
  __syncthreads();
  if (tid < 128)
    partial[((size_t)b * 16 + ch) * DM_ + tid] = ps[0][tid] + ps[1][tid] + ps[2][tid] + ps[3][tid];
}

// Final reduce + LN affine + classifier head. One block.
__global__ __launch_bounds__(256) void headk(
    const float* __restrict__ partial,
    const float* __restrict__ lng, const float* __restrict__ lnb,
    const float* __restrict__ c1w, const float* __restrict__ c1b,
    const float* __restrict__ c2w, const float* __restrict__ c2b,
    float* __restrict__ out)
{
  __shared__ float pool[16][128];
  __shared__ float p1[16][64];
  const int tid = threadIdx.x;
  for (int i = tid; i < 16 * 128; i += 256) {
    int b = i >> 7, dd = i & 127;
    float s = 0.f;
    for (int c = 0; c < 16; ++c) s += partial[((size_t)b * 16 + c) * DM_ + dd];
    pool[b][dd] = s * (1.f / (float)L_) * lng[dd] + lnb[dd];
  }
  __syncthreads();
  for (int i = tid; i < 16 * 64; i += 256) {
    int b = i >> 6, j = i & 63;
    float acc = c1b[j];
    for (int dd = 0; dd < 128; ++dd) acc += pool[b][dd] * c1w[j * 128 + dd];
    p1[b][j] = fmaxf(acc, 0.f);
  }
  __syncthreads();
  if (tid < 32) {
    int b = tid >> 1, k = tid & 1;
    float acc = c2b[k];
    for (int j = 0; j < 64; ++j) acc += p1[b][j] * c2w[k * 64 + j];
    out[b * 2 + k] = acc;
  }
}

// ---------------------------------------------------------------------------
extern "C" void kernel_launch(void* const* d_in, const int* in_sizes, int n_in,
                              void* d_out, int out_size, void* d_ws, size_t ws_size,
                              hipStream_t stream)
{
  (void)in_sizes; (void)n_in; (void)out_size; (void)ws_size;
  const float* x    = (const float*)d_in[0];
  const float* ipw  = (const float*)d_in[1];
  const float* ipb  = (const float*)d_in[2];
  const float* inw  = (const float*)d_in[3];
  const float* cw   = (const float*)d_in[4];
  const float* cb   = (const float*)d_in[5];
  const float* xpw  = (const float*)d_in[6];
  const float* dtw  = (const float*)d_in[7];
  const float* dtb  = (const float*)d_in[8];
  const float* alog = (const float*)d_in[9];
  const float* Dpv  = (const float*)d_in[10];
  const float* outw = (const float*)d_in[11];
  const float* lng  = (const float*)d_in[12];
  const float* lnb  = (const float*)d_in[13];
  const float* c1w  = (const float*)d_in[14];
  const float* c1b  = (const float*)d_in[15];
  const float* c2w  = (const float*)d_in[16];
  const float* c2b  = (const float*)d_in[17];

  float* ws = (float*)d_ws;
  const size_t SZ = (size_t)M_ * DM_;            // 8,388,608 floats
  float* h      = ws;                            // [M,128]
  float* yraw   = h + SZ;                        // u_raw, later reused as y
  float* zbuf   = yraw + SZ;                     // silu(z)
  float* ubuf   = zbuf + SZ;                     // post-conv u
  float* dbuf   = ubuf + SZ;                     // delta
  float* bc     = dbuf + SZ;                     // [M,32]
  float* hend   = bc + (size_t)M_ * 32;          // [B,NC,DM,16]
  float* hstart = hend + (size_t)B_ * NC_ * DM_ * NS_;
  float* Ssum   = hstart + (size_t)B_ * NC_ * DM_ * NS_;  // [B,NC,DM]
  float* part   = Ssum + (size_t)B_ * NC_ * DM_;

  // input projection: h = x @ ip_w^T + ip_b   (M x 128, K=1280)
  gemm_mfma<<<dim3(1, M_ / 128), 256, 0, stream>>>(
      x, ipw, ipb, h, nullptr, M_, DM_, DIN_, DM_, 0);

  for (int l = 0; l < NL_; ++l) {
    // in_proj -> u_raw (cols 0..127) and silu(z) (cols 128..255)
    gemm_mfma<<<dim3(2, M_ / 128), 256, 0, stream>>>(
        h, inw + (size_t)l * 256 * DM_, nullptr, yraw, zbuf, M_, 256, DM_, DM_, 0);
    xpc<<<M_ / 32, 256, 0, stream>>>(
        yraw, cw + l * DM_ * 2, cb + l * DM_,
        xpw + l * 40 * DM_, dtw + l * DM_ * RR_, dtb + l * DM_,
        ubuf, dbuf, bc);
    scan_h<<<dim3(NC_, B_), 128, 0, stream>>>(
        dbuf, ubuf, bc, alog + l * DM_ * NS_, hend, Ssum);
    scan_comb<<<(B_ * DM_ * NS_) / 256, 256, 0, stream>>>(
        hend, Ssum, alog + l * DM_ * NS_, hstart);
    scan_y<<<dim3(NC_, B_), 128, 0, stream>>>(
        dbuf, ubuf, zbuf, bc, alog + l * DM_ * NS_, Dpv + l * DM_, hstart, yraw);
    // out_proj with fused residual: h += y @ out_w^T
    gemm_mfma<<<dim3(1, M_ / 128), 256, 0, stream>>>(
        yraw, outw + (size_t)l * DM_ * DM_, nullptr, h, nullptr, M_, DM_, DM_, DM_, 1);
  }

  lnpool1<<<dim3(16, B_), 256, 0, stream>>>(h, part);
  headk<<<1, 256, 0, stream>>>(part, lng, lnb, c1w, c1b, c2w, c2b, (float*)d_out);
}